// Round 6
// baseline (342.801 us; speedup 1.0000x reference)
//
#include <hip/hip_runtime.h>
#include <cstddef>

#define B_DIM 4
#define T_DIM 2048
#define C_DIM 1024
#define H_DIM 16
#define D_DIM 64
#define C3_DIM 3072

typedef __attribute__((ext_vector_type(8))) __bf16 bf16x8;
typedef __attribute__((ext_vector_type(4))) __bf16 bf16x4;
typedef __attribute__((ext_vector_type(2))) __bf16 bf16x2;
typedef __attribute__((ext_vector_type(4))) float f32x4;

// ---------------------------------------------------------------------------
// fp32 -> bf16 elementwise (4 elems/thread)
// ---------------------------------------------------------------------------
__global__ __launch_bounds__(256) void cvt_bf16(const float* __restrict__ in,
                                                __bf16* __restrict__ out)
{
    int i = (blockIdx.x * 256 + threadIdx.x) * 4;
    float4 v = *(const float4*)&in[i];
    bf16x4 o = { (__bf16)v.x, (__bf16)v.y, (__bf16)v.z, (__bf16)v.w };
    *(bf16x4*)&out[i] = o;
}

// ---------------------------------------------------------------------------
// W[K][N] fp32 -> Wt[N][K] bf16 (64x64 LDS tile transpose)
// ---------------------------------------------------------------------------
__global__ __launch_bounds__(256) void transpose_cvt(
    const float* __restrict__ W, __bf16* __restrict__ Wt, int K, int N)
{
    __shared__ float tile[64][65];
    const int tid = threadIdx.x;
    const int n0 = blockIdx.x * 64, k0 = blockIdx.y * 64;
    const int tx = tid & 15, ty = tid >> 4;
#pragma unroll
    for (int it = 0; it < 4; ++it) {
        int r = it * 16 + ty;
        *(float4*)&tile[r][tx * 4] =
            *(const float4*)&W[(size_t)(k0 + r) * N + n0 + tx * 4];
    }
    __syncthreads();
    int c = tid >> 2, t0 = (tid & 3) * 16;
    __align__(16) __bf16 tmp[16];
#pragma unroll
    for (int j = 0; j < 16; ++j) tmp[j] = (__bf16)tile[t0 + j][c];
    __bf16* o = Wt + (size_t)(n0 + c) * K + k0 + t0;
    *(bf16x8*)o = *(bf16x8*)&tmp[0];
    *(bf16x8*)(o + 8) = *(bf16x8*)&tmp[8];
}

// ---------------------------------------------------------------------------
// bf16 MFMA GEMM v2: C[M,N] = A[M,K] @ Bt[N,K]^T + bias[N].
// 128x128 tile, BK=32, 4 waves. Register-prefetch staging (load k+1 into
// VGPRs after the barrier, ds_write at top of next iter -> vmcnt wait is one
// compute-phase ahead of use, not at the barrier). Operand-swapped MFMA so
// acc holds C^T -> vectorized epilogue (bf16x4 / float4 stores).
// ---------------------------------------------------------------------------
template <bool OUT_BF16>
__global__ __launch_bounds__(256) void gemm_bt(
    const __bf16* __restrict__ A, const __bf16* __restrict__ Bt,
    const float* __restrict__ bias, void* __restrict__ Cout,
    int M, int N, int K)
{
    __shared__ __align__(16) __bf16 Af[8][64][8];
    __shared__ __align__(16) __bf16 Bf[8][64][8];
    const int tid = threadIdx.x;
    const int lane = tid & 63, w = tid >> 6;
    const int lm = lane & 15, lq = lane >> 4;
    const int wm = w >> 1, wn = w & 1;
    const int m0 = blockIdx.y * 128, n0 = blockIdx.x * 128;

    const __bf16* a0 = A + (size_t)(m0 + w * 32 + lm) * K + lq * 8;
    const __bf16* a1 = a0 + (size_t)16 * K;
    const __bf16* b0 = Bt + (size_t)(n0 + w * 32 + lm) * K + lq * 8;
    const __bf16* b1 = b0 + (size_t)16 * K;

    f32x4 acc[4][4];
#pragma unroll
    for (int i = 0; i < 4; ++i)
#pragma unroll
        for (int j = 0; j < 4; ++j) acc[i][j] = (f32x4){0.f, 0.f, 0.f, 0.f};

    // preload k-tile 0 into registers
    bf16x8 ra0 = *(const bf16x8*)a0;
    bf16x8 ra1 = *(const bf16x8*)a1;
    bf16x8 rb0 = *(const bf16x8*)b0;
    bf16x8 rb1 = *(const bf16x8*)b1;

    for (int k0 = 0; k0 < K; k0 += 32) {
        __syncthreads();                 // prev iter's frag reads done
        *(bf16x8*)&Af[w * 2 + 0][lane][0] = ra0;
        *(bf16x8*)&Af[w * 2 + 1][lane][0] = ra1;
        *(bf16x8*)&Bf[w * 2 + 0][lane][0] = rb0;
        *(bf16x8*)&Bf[w * 2 + 1][lane][0] = rb1;
        __syncthreads();                 // staging visible

        // prefetch next k-tile (vmcnt wait lands at next iter's ds_write)
        int kn = (k0 + 32 < K) ? k0 + 32 : 0;
        ra0 = *(const bf16x8*)(a0 + kn);
        ra1 = *(const bf16x8*)(a1 + kn);
        rb0 = *(const bf16x8*)(b0 + kn);
        rb1 = *(const bf16x8*)(b1 + kn);

        bf16x8 av[4], bv[4];
#pragma unroll
        for (int i = 0; i < 4; ++i) {
            av[i] = *(const bf16x8*)&Af[wm * 4 + i][lane][0];
            bv[i] = *(const bf16x8*)&Bf[wn * 4 + i][lane][0];
        }
        // operand-swapped: acc[i][j] = C^T tile (rows=n, cols=m)
#pragma unroll
        for (int i = 0; i < 4; ++i)
#pragma unroll
            for (int j = 0; j < 4; ++j)
                acc[i][j] = __builtin_amdgcn_mfma_f32_16x16x32_bf16(
                    bv[j], av[i], acc[i][j], 0, 0, 0);
    }

    // epilogue: lane owns row m = ...+lm, cols n = ...+lq*4+0..3 per (i,j)
#pragma unroll
    for (int i = 0; i < 4; ++i) {
        size_t row = (size_t)(m0 + wm * 64 + i * 16 + lm);
#pragma unroll
        for (int j = 0; j < 4; ++j) {
            int col = n0 + wn * 64 + j * 16 + lq * 4;
            float4 b4 = *(const float4*)&bias[col];
            float v0 = acc[i][j][0] + b4.x;
            float v1 = acc[i][j][1] + b4.y;
            float v2 = acc[i][j][2] + b4.z;
            float v3 = acc[i][j][3] + b4.w;
            if (OUT_BF16) {
                bf16x4 o = { (__bf16)v0, (__bf16)v1, (__bf16)v2, (__bf16)v3 };
                *(bf16x4*)&((__bf16*)Cout)[row * N + col] = o;
            } else {
                float4 o = make_float4(v0, v1, v2, v3);
                *(float4*)&((float*)Cout)[row * N + col] = o;
            }
        }
    }
}

// ---------------------------------------------------------------------------
// RoPE on bf16 qkv: q rope'd * (0.125*log2e) in place (exp2-domain softmax);
// k rope'd -> Kb[bh][t][64]; v -> Vt[bh][64][t] (LDS transpose).
// ---------------------------------------------------------------------------
__global__ __launch_bounds__(256) void ropecvt(
    __bf16* qkv, __bf16* __restrict__ Kb, __bf16* __restrict__ Vt)
{
    __shared__ __bf16 vt[64][72];
    const int tid = threadIdx.x;
    const int t0 = blockIdx.x * 64;
    const int bh = blockIdx.y;
    const int b = bh >> 4, h = bh & 15;
    __bf16* base = qkv + ((size_t)(b * T_DIM + t0)) * C3_DIM + h * D_DIM;

    {
        int rr = tid >> 3, cc = (tid & 7) * 8;
#pragma unroll
        for (int it = 0; it < 2; ++it) {
            int r = it * 32 + rr;
            *(bf16x8*)&vt[r][cc] =
                *(const bf16x8*)&base[(size_t)r * C3_DIM + 2 * C_DIM + cc];
        }
    }

    const float QSCALE = 0.125f * 1.44269504089f;  // 1/sqrt(D) * log2(e)

#pragma unroll
    for (int p = 0; p < 8; ++p) {
        int idx = tid + p * 256;          // 64 t x 32 pairs
        int tl = idx >> 5, i = idx & 31;
        // theta = 10000^(-i/32) = exp2(-i * log2(1e4)/32)
        float theta = exp2f(-0.41524101186f * (float)i);
        float ang = (float)(t0 + tl) * theta;
        float s, c;
        __sincosf(ang, &s, &c);
        __bf16* qp = &base[(size_t)tl * C3_DIM + 2 * i];
        float qx = (float)qp[0], qy = (float)qp[1];
        bf16x2 qo = { (__bf16)((qx * c - qy * s) * QSCALE),
                      (__bf16)((qx * s + qy * c) * QSCALE) };
        *(bf16x2*)qp = qo;
        float kx = (float)qp[C_DIM], ky = (float)qp[C_DIM + 1];
        bf16x2 ko = { (__bf16)(kx * c - ky * s), (__bf16)(kx * s + ky * c) };
        *(bf16x2*)(Kb + ((size_t)bh * T_DIM + t0 + tl) * D_DIM + 2 * i) = ko;
    }

    __syncthreads();

    int dd = tid >> 2, tc0 = (tid & 3) * 16;
    __align__(16) __bf16 tmp[16];
#pragma unroll
    for (int j = 0; j < 16; ++j) tmp[j] = vt[tc0 + j][dd];
    __bf16* vo = Vt + ((size_t)bh * D_DIM + dd) * T_DIM + t0 + tc0;
    *(bf16x8*)vo = *(bf16x8*)&tmp[0];
    *(bf16x8*)(vo + 8) = *(bf16x8*)&tmp[8];
}

// ---------------------------------------------------------------------------
// MFMA flash attention v4: transposed-S dataflow (R5) + register-prefetch
// K/V staging: global->VGPR loads for tile kt+1 issued right after the
// staging barrier, ds_write at top of next iter. vmcnt wait overlaps the
// whole softmax+MFMA phase instead of stalling at the barrier.
// ---------------------------------------------------------------------------
__global__ __launch_bounds__(256) void attn_mfma(
    const __bf16* __restrict__ qkvb, const __bf16* __restrict__ Kb,
    const __bf16* __restrict__ Vt, __bf16* __restrict__ yb)
{
    __shared__ __align__(16) __bf16 Kf[8][64][8];   // 8 KB
    __shared__ __align__(16) __bf16 Vf[8][64][8];   // 8 KB
    __shared__ __align__(16) __bf16 Pb[4][16][72];  // 9.2 KB  [w][q][t]

    const int tid = threadIdx.x;
    const int bh = blockIdx.x;                  // 0..63
    const int qt = 31 - blockIdx.y;             // heavy first
    const int b = bh >> 4, h = bh & 15;
    const int lane = tid & 63, w = tid >> 6;
    const int m = lane & 15, qq = lane >> 4;

    // ---- Q B-fragments: direct global loads (pre-rope'd, pre-scaled)
    const __bf16* qrow = qkvb +
        ((size_t)(b * T_DIM + qt * 64 + w * 16 + m)) * C3_DIM + h * D_DIM + qq * 8;
    bf16x8 qreg[2];
    qreg[0] = *(const bf16x8*)qrow;
    qreg[1] = *(const bf16x8*)(qrow + 32);

    float m_i = -1e30f, l_i = 0.f;
    f32x4 acc[4];   // O^T: acc[db][r] = O[q=m][d=db*16+qq*4+r]
#pragma unroll
    for (int db = 0; db < 4; ++db) acc[db] = (f32x4){0.f, 0.f, 0.f, 0.f};

    const __bf16* kg0 = Kb + (size_t)bh * T_DIM * D_DIM +
                        (size_t)(w * 16 + m) * D_DIM + qq * 8;
    const __bf16* vg0 = Vt + (size_t)bh * D_DIM * T_DIM +
                        (size_t)(w * 16 + m) * T_DIM + qq * 8;

    // preload kt=0 K/V fragments into registers
    bf16x8 kr0 = *(const bf16x8*)(kg0);
    bf16x8 kr1 = *(const bf16x8*)(kg0 + 32);
    bf16x8 vr0 = *(const bf16x8*)(vg0);
    bf16x8 vr1 = *(const bf16x8*)(vg0 + 32);

    for (int kt = 0; kt <= qt; ++kt) {
        __syncthreads();   // all waves done reading Kf/Vf of prev iter
        *(bf16x8*)&Kf[w * 2 + 0][lane][0] = kr0;
        *(bf16x8*)&Kf[w * 2 + 1][lane][0] = kr1;
        *(bf16x8*)&Vf[w * 2 + 0][lane][0] = vr0;
        *(bf16x8*)&Vf[w * 2 + 1][lane][0] = vr1;
        __syncthreads();   // staging visible

        // prefetch next k-tile (waits overlap the compute below)
        int ktn = (kt < qt) ? kt + 1 : kt;
        kr0 = *(const bf16x8*)(kg0 + (size_t)ktn * 64 * D_DIM);
        kr1 = *(const bf16x8*)(kg0 + (size_t)ktn * 64 * D_DIM + 32);
        vr0 = *(const bf16x8*)(vg0 + ktn * 64);
        vr1 = *(const bf16x8*)(vg0 + ktn * 64 + 32);

        // ---- S^T = K @ Q^T : sv[nb][r] = S[q=m][t=nb*16+qq*4+r]
        f32x4 sv[4];
#pragma unroll
        for (int nb = 0; nb < 4; ++nb) {
            f32x4 s = (f32x4){0.f, 0.f, 0.f, 0.f};
            s = __builtin_amdgcn_mfma_f32_16x16x32_bf16(
                *(const bf16x8*)&Kf[nb * 2 + 0][lane][0], qreg[0], s, 0, 0, 0);
            s = __builtin_amdgcn_mfma_f32_16x16x32_bf16(
                *(const bf16x8*)&Kf[nb * 2 + 1][lane][0], qreg[1], s, 0, 0, 0);
            sv[nb] = s;
        }

        // ---- causal mask (diagonal tile): mask t_local > q_local
        if (kt == qt) {
            int qlocal = w * 16 + m;
#pragma unroll
            for (int nb = 0; nb < 4; ++nb) {
                int tb = nb * 16 + qq * 4;
#pragma unroll
                for (int r = 0; r < 4; ++r)
                    if (tb + r > qlocal) sv[nb][r] = -1e30f;
            }
        }

        // ---- online softmax: whole row in-lane; cross only over qq (2 shfl)
        float mt0 = fmaxf(fmaxf(sv[0][0], sv[0][1]), fmaxf(sv[0][2], sv[0][3]));
        float mt1 = fmaxf(fmaxf(sv[1][0], sv[1][1]), fmaxf(sv[1][2], sv[1][3]));
        float mt2 = fmaxf(fmaxf(sv[2][0], sv[2][1]), fmaxf(sv[2][2], sv[2][3]));
        float mt3 = fmaxf(fmaxf(sv[3][0], sv[3][1]), fmaxf(sv[3][2], sv[3][3]));
        float mt = fmaxf(fmaxf(mt0, mt1), fmaxf(mt2, mt3));
        mt = fmaxf(mt, __shfl_xor(mt, 16));
        mt = fmaxf(mt, __shfl_xor(mt, 32));
        float mnew = fmaxf(m_i, mt);
        float alpha = exp2f(m_i - mnew);
        float ll = 0.f;
#pragma unroll
        for (int nb = 0; nb < 4; ++nb) {
            float p0 = exp2f(sv[nb][0] - mnew);
            float p1 = exp2f(sv[nb][1] - mnew);
            float p2 = exp2f(sv[nb][2] - mnew);
            float p3 = exp2f(sv[nb][3] - mnew);
            sv[nb][0] = p0; sv[nb][1] = p1; sv[nb][2] = p2; sv[nb][3] = p3;
            ll += (p0 + p1) + (p2 + p3);
        }
        ll += __shfl_xor(ll, 16);
        ll += __shfl_xor(ll, 32);
        l_i = l_i * alpha + ll;
        m_i = mnew;
#pragma unroll
        for (int db = 0; db < 4; ++db) {
            acc[db][0] *= alpha; acc[db][1] *= alpha;
            acc[db][2] *= alpha; acc[db][3] *= alpha;
        }

        // ---- P[q][t] write: contiguous in t -> 4x b64
#pragma unroll
        for (int nb = 0; nb < 4; ++nb) {
            bf16x4 pv = { (__bf16)sv[nb][0], (__bf16)sv[nb][1],
                          (__bf16)sv[nb][2], (__bf16)sv[nb][3] };
            *(bf16x4*)&Pb[w][m][nb * 16 + qq * 4] = pv;
        }

        // ---- P^T B-fragments (b128, same-wave round trip)
        bf16x8 pf0 = *(const bf16x8*)&Pb[w][m][0 * 32 + qq * 8];
        bf16x8 pf1 = *(const bf16x8*)&Pb[w][m][1 * 32 + qq * 8];

        // ---- O^T += V^T @ P^T
#pragma unroll
        for (int db = 0; db < 4; ++db) {
            acc[db] = __builtin_amdgcn_mfma_f32_16x16x32_bf16(
                *(const bf16x8*)&Vf[db * 2 + 0][lane][0], pf0, acc[db], 0, 0, 0);
            acc[db] = __builtin_amdgcn_mfma_f32_16x16x32_bf16(
                *(const bf16x8*)&Vf[db * 2 + 1][lane][0], pf1, acc[db], 0, 0, 0);
        }
    }

    // ---- epilogue: O[q=m][d]; 4x 8B stores
    float inv = 1.0f / l_i;
    __bf16* yrow = yb + (size_t)(b * T_DIM + qt * 64 + w * 16 + m) * C_DIM +
                   h * D_DIM + qq * 4;
#pragma unroll
    for (int db = 0; db < 4; ++db) {
        bf16x4 o = { (__bf16)(acc[db][0] * inv), (__bf16)(acc[db][1] * inv),
                     (__bf16)(acc[db][2] * inv), (__bf16)(acc[db][3] * inv) };
        *(bf16x4*)(yrow + db * 16) = o;
    }
}

// ---------------------------------------------------------------------------
extern "C" void kernel_launch(void* const* d_in, const int* in_sizes, int n_in,
                              void* d_out, int out_size, void* d_ws, size_t ws_size,
                              hipStream_t stream)
{
    const float* x     = (const float*)d_in[0];
    const float* Wqkv  = (const float*)d_in[1];
    const float* bqkv  = (const float*)d_in[2];
    const float* Wproj = (const float*)d_in[3];
    const float* bproj = (const float*)d_in[4];
    float* out = (float*)d_out;

    char* ws = (char*)d_ws;
    __bf16* qkvb = (__bf16*)(ws);                        // [8192][3072] 48 MB
    __bf16* xb   = (__bf16*)(ws + 50331648ull);          // [8192][1024] 16 MB
    __bf16* yb   = (__bf16*)(ws + 67108864ull);          // [8192][1024] 16 MB
    __bf16* Kb   = (__bf16*)(ws + 83886080ull);          // [64][2048][64] 16 MB
    __bf16* Vt   = (__bf16*)(ws + 100663296ull);         // [64][64][2048] 16 MB
    __bf16* Wqt  = (__bf16*)(ws + 117440512ull);         // [3072][1024] 6 MB
    __bf16* Wpt  = (__bf16*)(ws + 123731968ull);         // [1024][1024] 2 MB

    dim3 blk(256);

    cvt_bf16<<<dim3((B_DIM * T_DIM * C_DIM) / 1024), blk, 0, stream>>>(x, xb);
    transpose_cvt<<<dim3(C3_DIM / 64, C_DIM / 64), blk, 0, stream>>>(
        Wqkv, Wqt, C_DIM, C3_DIM);
    transpose_cvt<<<dim3(C_DIM / 64, C_DIM / 64), blk, 0, stream>>>(
        Wproj, Wpt, C_DIM, C_DIM);

    gemm_bt<true><<<dim3(C3_DIM / 128, (B_DIM * T_DIM) / 128), blk, 0, stream>>>(
        xb, Wqt, bqkv, qkvb, B_DIM * T_DIM, C3_DIM, C_DIM);

    ropecvt<<<dim3(T_DIM / 64, B_DIM * H_DIM), blk, 0, stream>>>(qkvb, Kb, Vt);

    attn_mfma<<<dim3(B_DIM * H_DIM, T_DIM / 64), blk, 0, stream>>>(
        qkvb, Kb, Vt, yb);

    gemm_bt<false><<<dim3(C_DIM / 128, (B_DIM * T_DIM) / 128), blk, 0, stream>>>(
        yb, Wpt, bproj, out, B_DIM * T_DIM, C_DIM, C_DIM);
}

// Round 7
// 337.742 us; speedup vs baseline: 1.0150x; 1.0150x over previous
//
#include <hip/hip_runtime.h>
#include <cstddef>

#define B_DIM 4
#define T_DIM 2048
#define C_DIM 1024
#define H_DIM 16
#define D_DIM 64
#define C3_DIM 3072

typedef __attribute__((ext_vector_type(8))) __bf16 bf16x8;
typedef __attribute__((ext_vector_type(4))) __bf16 bf16x4;
typedef __attribute__((ext_vector_type(2))) __bf16 bf16x2;
typedef __attribute__((ext_vector_type(4))) float f32x4;

typedef const __attribute__((address_space(1))) unsigned int* gptr_t;
typedef __attribute__((address_space(3))) unsigned int* lptr_t;

// ---------------------------------------------------------------------------
// fp32 -> bf16 elementwise (4 elems/thread)
// ---------------------------------------------------------------------------
__global__ __launch_bounds__(256) void cvt_bf16(const float* __restrict__ in,
                                                __bf16* __restrict__ out)
{
    int i = (blockIdx.x * 256 + threadIdx.x) * 4;
    float4 v = *(const float4*)&in[i];
    bf16x4 o = { (__bf16)v.x, (__bf16)v.y, (__bf16)v.z, (__bf16)v.w };
    *(bf16x4*)&out[i] = o;
}

// ---------------------------------------------------------------------------
// W[K][N] fp32 -> Wt[N][K] bf16 (64x64 LDS tile transpose)
// ---------------------------------------------------------------------------
__global__ __launch_bounds__(256) void transpose_cvt(
    const float* __restrict__ W, __bf16* __restrict__ Wt, int K, int N)
{
    __shared__ float tile[64][65];
    const int tid = threadIdx.x;
    const int n0 = blockIdx.x * 64, k0 = blockIdx.y * 64;
    const int tx = tid & 15, ty = tid >> 4;
#pragma unroll
    for (int it = 0; it < 4; ++it) {
        int r = it * 16 + ty;
        *(float4*)&tile[r][tx * 4] =
            *(const float4*)&W[(size_t)(k0 + r) * N + n0 + tx * 4];
    }
    __syncthreads();
    int c = tid >> 2, t0 = (tid & 3) * 16;
    __align__(16) __bf16 tmp[16];
#pragma unroll
    for (int j = 0; j < 16; ++j) tmp[j] = (__bf16)tile[t0 + j][c];
    __bf16* o = Wt + (size_t)(n0 + c) * K + k0 + t0;
    *(bf16x8*)o = *(bf16x8*)&tmp[0];
    *(bf16x8*)(o + 8) = *(bf16x8*)&tmp[8];
}

// ---------------------------------------------------------------------------
// bf16 MFMA GEMM v3: C[M,N] = A[M,K] @ Bt[N,K]^T + bias[N].
// 128x128 tile, BK=64 (2 MFMA k-steps per staging phase -> half the barrier
// drains of BK=32), global_load_lds width=16 staging (R5-proven; the R6
// register-prefetch variant regressed). Operand-swapped MFMA -> C^T acc ->
// vectorized epilogue. LDS 32 KB.
// Slot layout: Xf[sub*2+ks][lane][8]; sub = 16-row subtile 0..7, ks = k-step.
// ---------------------------------------------------------------------------
template <bool OUT_BF16>
__global__ __launch_bounds__(256) void gemm_bt(
    const __bf16* __restrict__ A, const __bf16* __restrict__ Bt,
    const float* __restrict__ bias, void* __restrict__ Cout,
    int M, int N, int K)
{
    __shared__ __align__(16) __bf16 Af[16][64][8];   // 16 KB
    __shared__ __align__(16) __bf16 Bf[16][64][8];   // 16 KB
    const int tid = threadIdx.x;
    const int lane = tid & 63, w = tid >> 6;
    const int lm = lane & 15, lq = lane >> 4;
    const int wm = w >> 1, wn = w & 1;
    const int m0 = blockIdx.y * 128, n0 = blockIdx.x * 128;

    // wave w stages A subtiles {2w,2w+1} and B subtiles {2w,2w+1}, both k-steps
    const __bf16* a0 = A + (size_t)(m0 + w * 32 + lm) * K + lq * 8;
    const __bf16* a1 = a0 + (size_t)16 * K;
    const __bf16* b0 = Bt + (size_t)(n0 + w * 32 + lm) * K + lq * 8;
    const __bf16* b1 = b0 + (size_t)16 * K;

    f32x4 acc[4][4];
#pragma unroll
    for (int i = 0; i < 4; ++i)
#pragma unroll
        for (int j = 0; j < 4; ++j) acc[i][j] = (f32x4){0.f, 0.f, 0.f, 0.f};

    for (int k0 = 0; k0 < K; k0 += 64) {
        __syncthreads();
        __builtin_amdgcn_global_load_lds((gptr_t)(const void*)(a0 + k0),
            (lptr_t)(void*)&Af[4 * w + 0][0][0], 16, 0, 0);
        __builtin_amdgcn_global_load_lds((gptr_t)(const void*)(a0 + k0 + 32),
            (lptr_t)(void*)&Af[4 * w + 1][0][0], 16, 0, 0);
        __builtin_amdgcn_global_load_lds((gptr_t)(const void*)(a1 + k0),
            (lptr_t)(void*)&Af[4 * w + 2][0][0], 16, 0, 0);
        __builtin_amdgcn_global_load_lds((gptr_t)(const void*)(a1 + k0 + 32),
            (lptr_t)(void*)&Af[4 * w + 3][0][0], 16, 0, 0);
        __builtin_amdgcn_global_load_lds((gptr_t)(const void*)(b0 + k0),
            (lptr_t)(void*)&Bf[4 * w + 0][0][0], 16, 0, 0);
        __builtin_amdgcn_global_load_lds((gptr_t)(const void*)(b0 + k0 + 32),
            (lptr_t)(void*)&Bf[4 * w + 1][0][0], 16, 0, 0);
        __builtin_amdgcn_global_load_lds((gptr_t)(const void*)(b1 + k0),
            (lptr_t)(void*)&Bf[4 * w + 2][0][0], 16, 0, 0);
        __builtin_amdgcn_global_load_lds((gptr_t)(const void*)(b1 + k0 + 32),
            (lptr_t)(void*)&Bf[4 * w + 3][0][0], 16, 0, 0);
        __syncthreads();

#pragma unroll
        for (int ks = 0; ks < 2; ++ks) {
            bf16x8 av[4], bv[4];
#pragma unroll
            for (int i = 0; i < 4; ++i) {
                av[i] = *(const bf16x8*)&Af[(wm * 4 + i) * 2 + ks][lane][0];
                bv[i] = *(const bf16x8*)&Bf[(wn * 4 + i) * 2 + ks][lane][0];
            }
            // operand-swapped: acc[i][j] holds C^T (rows=n, cols=m)
#pragma unroll
            for (int i = 0; i < 4; ++i)
#pragma unroll
                for (int j = 0; j < 4; ++j)
                    acc[i][j] = __builtin_amdgcn_mfma_f32_16x16x32_bf16(
                        bv[j], av[i], acc[i][j], 0, 0, 0);
        }
    }

    // epilogue: lane owns row m = ...+lm, cols n = ...+lq*4+0..3 per (i,j)
#pragma unroll
    for (int i = 0; i < 4; ++i) {
        size_t row = (size_t)(m0 + wm * 64 + i * 16 + lm);
#pragma unroll
        for (int j = 0; j < 4; ++j) {
            int col = n0 + wn * 64 + j * 16 + lq * 4;
            float4 b4 = *(const float4*)&bias[col];
            float v0 = acc[i][j][0] + b4.x;
            float v1 = acc[i][j][1] + b4.y;
            float v2 = acc[i][j][2] + b4.z;
            float v3 = acc[i][j][3] + b4.w;
            if (OUT_BF16) {
                bf16x4 o = { (__bf16)v0, (__bf16)v1, (__bf16)v2, (__bf16)v3 };
                *(bf16x4*)&((__bf16*)Cout)[row * N + col] = o;
            } else {
                float4 o = make_float4(v0, v1, v2, v3);
                *(float4*)&((float*)Cout)[row * N + col] = o;
            }
        }
    }
}

// ---------------------------------------------------------------------------
// RoPE on bf16 qkv: q rope'd * (0.125*log2e) in place (exp2-domain softmax);
// k rope'd -> Kb[bh][t][64]; v -> Vt[bh][64][t] (LDS transpose).
// ---------------------------------------------------------------------------
__global__ __launch_bounds__(256) void ropecvt(
    __bf16* qkv, __bf16* __restrict__ Kb, __bf16* __restrict__ Vt)
{
    __shared__ __bf16 vt[64][72];
    const int tid = threadIdx.x;
    const int t0 = blockIdx.x * 64;
    const int bh = blockIdx.y;
    const int b = bh >> 4, h = bh & 15;
    __bf16* base = qkv + ((size_t)(b * T_DIM + t0)) * C3_DIM + h * D_DIM;

    {
        int rr = tid >> 3, cc = (tid & 7) * 8;
#pragma unroll
        for (int it = 0; it < 2; ++it) {
            int r = it * 32 + rr;
            *(bf16x8*)&vt[r][cc] =
                *(const bf16x8*)&base[(size_t)r * C3_DIM + 2 * C_DIM + cc];
        }
    }

    const float QSCALE = 0.125f * 1.44269504089f;  // 1/sqrt(D) * log2(e)

#pragma unroll
    for (int p = 0; p < 8; ++p) {
        int idx = tid + p * 256;          // 64 t x 32 pairs
        int tl = idx >> 5, i = idx & 31;
        float theta = exp2f(-0.41524101186f * (float)i);
        float ang = (float)(t0 + tl) * theta;
        float s, c;
        __sincosf(ang, &s, &c);
        __bf16* qp = &base[(size_t)tl * C3_DIM + 2 * i];
        float qx = (float)qp[0], qy = (float)qp[1];
        bf16x2 qo = { (__bf16)((qx * c - qy * s) * QSCALE),
                      (__bf16)((qx * s + qy * c) * QSCALE) };
        *(bf16x2*)qp = qo;
        float kx = (float)qp[C_DIM], ky = (float)qp[C_DIM + 1];
        bf16x2 ko = { (__bf16)(kx * c - ky * s), (__bf16)(kx * s + ky * c) };
        *(bf16x2*)(Kb + ((size_t)bh * T_DIM + t0 + tl) * D_DIM + 2 * i) = ko;
    }

    __syncthreads();

    int dd = tid >> 2, tc0 = (tid & 3) * 16;
    __align__(16) __bf16 tmp[16];
#pragma unroll
    for (int j = 0; j < 16; ++j) tmp[j] = vt[tc0 + j][dd];
    __bf16* vo = Vt + ((size_t)bh * D_DIM + dd) * T_DIM + t0 + tc0;
    *(bf16x8*)vo = *(bf16x8*)&tmp[0];
    *(bf16x8*)(vo + 8) = *(bf16x8*)&tmp[8];
}

// ---------------------------------------------------------------------------
// MFMA flash attention v4 (kept from R6): transposed-S dataflow + register-
// prefetch K/V staging (helped here: long softmax compute phase overlaps the
// prefetch loads; total-time accounting showed ~-20us vs R5).
// ---------------------------------------------------------------------------
__global__ __launch_bounds__(256) void attn_mfma(
    const __bf16* __restrict__ qkvb, const __bf16* __restrict__ Kb,
    const __bf16* __restrict__ Vt, __bf16* __restrict__ yb)
{
    __shared__ __align__(16) __bf16 Kf[8][64][8];   // 8 KB
    __shared__ __align__(16) __bf16 Vf[8][64][8];   // 8 KB
    __shared__ __align__(16) __bf16 Pb[4][16][72];  // 9.2 KB  [w][q][t]

    const int tid = threadIdx.x;
    const int bh = blockIdx.x;                  // 0..63
    const int qt = 31 - blockIdx.y;             // heavy first
    const int b = bh >> 4, h = bh & 15;
    const int lane = tid & 63, w = tid >> 6;
    const int m = lane & 15, qq = lane >> 4;

    const __bf16* qrow = qkvb +
        ((size_t)(b * T_DIM + qt * 64 + w * 16 + m)) * C3_DIM + h * D_DIM + qq * 8;
    bf16x8 qreg[2];
    qreg[0] = *(const bf16x8*)qrow;
    qreg[1] = *(const bf16x8*)(qrow + 32);

    float m_i = -1e30f, l_i = 0.f;
    f32x4 acc[4];   // O^T: acc[db][r] = O[q=m][d=db*16+qq*4+r]
#pragma unroll
    for (int db = 0; db < 4; ++db) acc[db] = (f32x4){0.f, 0.f, 0.f, 0.f};

    const __bf16* kg0 = Kb + (size_t)bh * T_DIM * D_DIM +
                        (size_t)(w * 16 + m) * D_DIM + qq * 8;
    const __bf16* vg0 = Vt + (size_t)bh * D_DIM * T_DIM +
                        (size_t)(w * 16 + m) * T_DIM + qq * 8;

    bf16x8 kr0 = *(const bf16x8*)(kg0);
    bf16x8 kr1 = *(const bf16x8*)(kg0 + 32);
    bf16x8 vr0 = *(const bf16x8*)(vg0);
    bf16x8 vr1 = *(const bf16x8*)(vg0 + 32);

    for (int kt = 0; kt <= qt; ++kt) {
        __syncthreads();
        *(bf16x8*)&Kf[w * 2 + 0][lane][0] = kr0;
        *(bf16x8*)&Kf[w * 2 + 1][lane][0] = kr1;
        *(bf16x8*)&Vf[w * 2 + 0][lane][0] = vr0;
        *(bf16x8*)&Vf[w * 2 + 1][lane][0] = vr1;
        __syncthreads();

        int ktn = (kt < qt) ? kt + 1 : kt;
        kr0 = *(const bf16x8*)(kg0 + (size_t)ktn * 64 * D_DIM);
        kr1 = *(const bf16x8*)(kg0 + (size_t)ktn * 64 * D_DIM + 32);
        vr0 = *(const bf16x8*)(vg0 + ktn * 64);
        vr1 = *(const bf16x8*)(vg0 + ktn * 64 + 32);

        // ---- S^T = K @ Q^T : sv[nb][r] = S[q=m][t=nb*16+qq*4+r]
        f32x4 sv[4];
#pragma unroll
        for (int nb = 0; nb < 4; ++nb) {
            f32x4 s = (f32x4){0.f, 0.f, 0.f, 0.f};
            s = __builtin_amdgcn_mfma_f32_16x16x32_bf16(
                *(const bf16x8*)&Kf[nb * 2 + 0][lane][0], qreg[0], s, 0, 0, 0);
            s = __builtin_amdgcn_mfma_f32_16x16x32_bf16(
                *(const bf16x8*)&Kf[nb * 2 + 1][lane][0], qreg[1], s, 0, 0, 0);
            sv[nb] = s;
        }

        if (kt == qt) {
            int qlocal = w * 16 + m;
#pragma unroll
            for (int nb = 0; nb < 4; ++nb) {
                int tb = nb * 16 + qq * 4;
#pragma unroll
                for (int r = 0; r < 4; ++r)
                    if (tb + r > qlocal) sv[nb][r] = -1e30f;
            }
        }

        float mt0 = fmaxf(fmaxf(sv[0][0], sv[0][1]), fmaxf(sv[0][2], sv[0][3]));
        float mt1 = fmaxf(fmaxf(sv[1][0], sv[1][1]), fmaxf(sv[1][2], sv[1][3]));
        float mt2 = fmaxf(fmaxf(sv[2][0], sv[2][1]), fmaxf(sv[2][2], sv[2][3]));
        float mt3 = fmaxf(fmaxf(sv[3][0], sv[3][1]), fmaxf(sv[3][2], sv[3][3]));
        float mt = fmaxf(fmaxf(mt0, mt1), fmaxf(mt2, mt3));
        mt = fmaxf(mt, __shfl_xor(mt, 16));
        mt = fmaxf(mt, __shfl_xor(mt, 32));
        float mnew = fmaxf(m_i, mt);
        float alpha = exp2f(m_i - mnew);
        float ll = 0.f;
#pragma unroll
        for (int nb = 0; nb < 4; ++nb) {
            float p0 = exp2f(sv[nb][0] - mnew);
            float p1 = exp2f(sv[nb][1] - mnew);
            float p2 = exp2f(sv[nb][2] - mnew);
            float p3 = exp2f(sv[nb][3] - mnew);
            sv[nb][0] = p0; sv[nb][1] = p1; sv[nb][2] = p2; sv[nb][3] = p3;
            ll += (p0 + p1) + (p2 + p3);
        }
        ll += __shfl_xor(ll, 16);
        ll += __shfl_xor(ll, 32);
        l_i = l_i * alpha + ll;
        m_i = mnew;
#pragma unroll
        for (int db = 0; db < 4; ++db) {
            acc[db][0] *= alpha; acc[db][1] *= alpha;
            acc[db][2] *= alpha; acc[db][3] *= alpha;
        }

#pragma unroll
        for (int nb = 0; nb < 4; ++nb) {
            bf16x4 pv = { (__bf16)sv[nb][0], (__bf16)sv[nb][1],
                          (__bf16)sv[nb][2], (__bf16)sv[nb][3] };
            *(bf16x4*)&Pb[w][m][nb * 16 + qq * 4] = pv;
        }

        bf16x8 pf0 = *(const bf16x8*)&Pb[w][m][0 * 32 + qq * 8];
        bf16x8 pf1 = *(const bf16x8*)&Pb[w][m][1 * 32 + qq * 8];

#pragma unroll
        for (int db = 0; db < 4; ++db) {
            acc[db] = __builtin_amdgcn_mfma_f32_16x16x32_bf16(
                *(const bf16x8*)&Vf[db * 2 + 0][lane][0], pf0, acc[db], 0, 0, 0);
            acc[db] = __builtin_amdgcn_mfma_f32_16x16x32_bf16(
                *(const bf16x8*)&Vf[db * 2 + 1][lane][0], pf1, acc[db], 0, 0, 0);
        }
    }

    float inv = 1.0f / l_i;
    __bf16* yrow = yb + (size_t)(b * T_DIM + qt * 64 + w * 16 + m) * C_DIM +
                   h * D_DIM + qq * 4;
#pragma unroll
    for (int db = 0; db < 4; ++db) {
        bf16x4 o = { (__bf16)(acc[db][0] * inv), (__bf16)(acc[db][1] * inv),
                     (__bf16)(acc[db][2] * inv), (__bf16)(acc[db][3] * inv) };
        *(bf16x4*)(yrow + db * 16) = o;
    }
}

// ---------------------------------------------------------------------------
extern "C" void kernel_launch(void* const* d_in, const int* in_sizes, int n_in,
                              void* d_out, int out_size, void* d_ws, size_t ws_size,
                              hipStream_t stream)
{
    const float* x     = (const float*)d_in[0];
    const float* Wqkv  = (const float*)d_in[1];
    const float* bqkv  = (const float*)d_in[2];
    const float* Wproj = (const float*)d_in[3];
    const float* bproj = (const float*)d_in[4];
    float* out = (float*)d_out;

    char* ws = (char*)d_ws;
    __bf16* qkvb = (__bf16*)(ws);                        // [8192][3072] 48 MB
    __bf16* xb   = (__bf16*)(ws + 50331648ull);          // [8192][1024] 16 MB
    __bf16* yb   = (__bf16*)(ws + 67108864ull);          // [8192][1024] 16 MB
    __bf16* Kb   = (__bf16*)(ws + 83886080ull);          // [64][2048][64] 16 MB
    __bf16* Vt   = (__bf16*)(ws + 100663296ull);         // [64][64][2048] 16 MB
    __bf16* Wqt  = (__bf16*)(ws + 117440512ull);         // [3072][1024] 6 MB
    __bf16* Wpt  = (__bf16*)(ws + 123731968ull);         // [1024][1024] 2 MB

    dim3 blk(256);

    cvt_bf16<<<dim3((B_DIM * T_DIM * C_DIM) / 1024), blk, 0, stream>>>(x, xb);
    transpose_cvt<<<dim3(C3_DIM / 64, C_DIM / 64), blk, 0, stream>>>(
        Wqkv, Wqt, C_DIM, C3_DIM);
    transpose_cvt<<<dim3(C_DIM / 64, C_DIM / 64), blk, 0, stream>>>(
        Wproj, Wpt, C_DIM, C_DIM);

    gemm_bt<true><<<dim3(C3_DIM / 128, (B_DIM * T_DIM) / 128), blk, 0, stream>>>(
        xb, Wqt, bqkv, qkvb, B_DIM * T_DIM, C3_DIM, C_DIM);

    ropecvt<<<dim3(T_DIM / 64, B_DIM * H_DIM), blk, 0, stream>>>(qkvb, Kb, Vt);

    attn_mfma<<<dim3(B_DIM * H_DIM, T_DIM / 64), blk, 0, stream>>>(
        qkvb, Kb, Vt, yb);

    gemm_bt<false><<<dim3(C_DIM / 128, (B_DIM * T_DIM) / 128), blk, 0, stream>>>(
        yb, Wpt, bproj, out, B_DIM * T_DIM, C_DIM, C_DIM);
}

// Round 8
// 316.999 us; speedup vs baseline: 1.0814x; 1.0654x over previous
//
#include <hip/hip_runtime.h>
#include <cstddef>

#define B_DIM 4
#define T_DIM 2048
#define C_DIM 1024
#define H_DIM 16
#define D_DIM 64
#define C3_DIM 3072

typedef __attribute__((ext_vector_type(8))) __bf16 bf16x8;
typedef __attribute__((ext_vector_type(4))) __bf16 bf16x4;
typedef __attribute__((ext_vector_type(2))) __bf16 bf16x2;
typedef __attribute__((ext_vector_type(4))) float f32x4;

typedef const __attribute__((address_space(1))) unsigned int* gptr_t;
typedef __attribute__((address_space(3))) unsigned int* lptr_t;

#define QSCALE 0.180336850073f      /* (1/sqrt(64)) * log2(e) */
#define NTHETA 0.41524101186f       /* log2(10000)/32 */

// ---------------------------------------------------------------------------
// prep: x -> xb bf16 (blocks 0..8191); Wqkv -> Wqt^T bf16 (8192..8959);
// Wproj -> Wpt^T bf16 (8960..9215). One dispatch replaces three.
// ---------------------------------------------------------------------------
__global__ __launch_bounds__(256) void prep(
    const float* __restrict__ x, __bf16* __restrict__ xb,
    const float* __restrict__ Wq, __bf16* __restrict__ Wqt,
    const float* __restrict__ Wp, __bf16* __restrict__ Wpt)
{
    __shared__ float tile[64][65];
    const int z = blockIdx.x, tid = threadIdx.x;

    if (z < 8192) {
        size_t i = (size_t)z * 1024 + tid * 4;
        float4 v = *(const float4*)&x[i];
        bf16x4 o = { (__bf16)v.x, (__bf16)v.y, (__bf16)v.z, (__bf16)v.w };
        *(bf16x4*)&xb[i] = o;
        return;
    }

    const float* W;
    __bf16* Wt;
    int N, idx;
    if (z < 8960) { W = Wq; Wt = Wqt; N = C3_DIM; idx = z - 8192; }
    else          { W = Wp; Wt = Wpt; N = C_DIM;  idx = z - 8960; }
    const int K = C_DIM;
    const int nblk = N / 64;
    const int n0 = (idx % nblk) * 64, k0 = (idx / nblk) * 64;

    const int tx = tid & 15, ty = tid >> 4;
#pragma unroll
    for (int it = 0; it < 4; ++it) {
        int r = it * 16 + ty;
        *(float4*)&tile[r][tx * 4] =
            *(const float4*)&W[(size_t)(k0 + r) * N + n0 + tx * 4];
    }
    __syncthreads();
    int c = tid >> 2, t0 = (tid & 3) * 16;
    __align__(16) __bf16 tmp[16];
#pragma unroll
    for (int j = 0; j < 16; ++j) tmp[j] = (__bf16)tile[t0 + j][c];
    __bf16* o = Wt + (size_t)(n0 + c) * K + k0 + t0;
    *(bf16x8*)o = *(bf16x8*)&tmp[0];
    *(bf16x8*)(o + 8) = *(bf16x8*)&tmp[8];
}

// ---------------------------------------------------------------------------
// Fused QKV GEMM + bias + RoPE + repack.
// 128x128 tile, BK=32, DMA staging (R5-proven loop).
// q/k column-tiles (n0<2048): swapped MFMA -> C^T acc (lane: 1 t, 4 consec d)
//   -> in-register RoPE on fp32 -> Qb/Kb[bh][t][64] bf16x4 stores.
// v tiles (n0>=2048): unswapped MFMA -> C acc (lane: 4 consec t, 1 d)
//   -> direct transposed Vt[bh][d][t] bf16x4 stores (no LDS bounce).
// ---------------------------------------------------------------------------
__global__ __launch_bounds__(256) void gemm_qkv(
    const __bf16* __restrict__ A, const __bf16* __restrict__ Bt,
    const float* __restrict__ bias,
    __bf16* __restrict__ Qb, __bf16* __restrict__ Kb, __bf16* __restrict__ Vt)
{
    __shared__ __align__(16) __bf16 Af[8][64][8];
    __shared__ __align__(16) __bf16 Bf[8][64][8];
    const int tid = threadIdx.x;
    const int lane = tid & 63, w = tid >> 6;
    const int lm = lane & 15, lq = lane >> 4;
    const int wm = w >> 1, wn = w & 1;
    const int m0 = blockIdx.y * 128, n0 = blockIdx.x * 128;
    const int K = C_DIM;

    const __bf16* a0 = A + (size_t)(m0 + w * 32 + lm) * K + lq * 8;
    const __bf16* a1 = a0 + (size_t)16 * K;
    const __bf16* b0 = Bt + (size_t)(n0 + w * 32 + lm) * K + lq * 8;
    const __bf16* b1 = b0 + (size_t)16 * K;

    f32x4 acc[4][4];
#pragma unroll
    for (int i = 0; i < 4; ++i)
#pragma unroll
        for (int j = 0; j < 4; ++j) acc[i][j] = (f32x4){0.f, 0.f, 0.f, 0.f};

    const bool is_v = (n0 >= 2 * C_DIM);

    if (!is_v) {
        for (int k0 = 0; k0 < K; k0 += 32) {
            __syncthreads();
            __builtin_amdgcn_global_load_lds((gptr_t)(const void*)(a0 + k0),
                (lptr_t)(void*)&Af[w * 2 + 0][0][0], 16, 0, 0);
            __builtin_amdgcn_global_load_lds((gptr_t)(const void*)(a1 + k0),
                (lptr_t)(void*)&Af[w * 2 + 1][0][0], 16, 0, 0);
            __builtin_amdgcn_global_load_lds((gptr_t)(const void*)(b0 + k0),
                (lptr_t)(void*)&Bf[w * 2 + 0][0][0], 16, 0, 0);
            __builtin_amdgcn_global_load_lds((gptr_t)(const void*)(b1 + k0),
                (lptr_t)(void*)&Bf[w * 2 + 1][0][0], 16, 0, 0);
            __syncthreads();
            bf16x8 av[4], bv[4];
#pragma unroll
            for (int i = 0; i < 4; ++i) {
                av[i] = *(const bf16x8*)&Af[wm * 4 + i][lane][0];
                bv[i] = *(const bf16x8*)&Bf[wn * 4 + i][lane][0];
            }
#pragma unroll
            for (int i = 0; i < 4; ++i)
#pragma unroll
                for (int j = 0; j < 4; ++j)
                    acc[i][j] = __builtin_amdgcn_mfma_f32_16x16x32_bf16(
                        bv[j], av[i], acc[i][j], 0, 0, 0);
        }

        // ---- epilogue: acc[i][j][r] = C[t = m0+wm*64+i*16+lm]
        //                               [col = n0+wn*64+j*16+lq*4+r]
        const bool is_q = (n0 < C_DIM);
        const float scale = is_q ? QSCALE : 1.0f;
        __bf16* dstbase = is_q ? Qb : Kb;
#pragma unroll
        for (int j = 0; j < 4; ++j) {
            int col = n0 + wn * 64 + j * 16 + lq * 4;
            int d0 = col & 63;
            int h = (col & (C_DIM - 1)) >> 6;
            float4 b4 = *(const float4*)&bias[col];
            float th0 = exp2f(-NTHETA * (float)(d0 >> 1));
            float th1 = exp2f(-NTHETA * (float)((d0 >> 1) + 1));
#pragma unroll
            for (int i = 0; i < 4; ++i) {
                int tg = m0 + wm * 64 + i * 16 + lm;
                int bb = tg >> 11, tl = tg & (T_DIM - 1);
                float v0 = acc[i][j][0] + b4.x;
                float v1 = acc[i][j][1] + b4.y;
                float v2 = acc[i][j][2] + b4.z;
                float v3 = acc[i][j][3] + b4.w;
                float s0, c0, s1, c1;
                __sincosf((float)tl * th0, &s0, &c0);
                __sincosf((float)tl * th1, &s1, &c1);
                bf16x4 o = { (__bf16)((v0 * c0 - v1 * s0) * scale),
                             (__bf16)((v0 * s0 + v1 * c0) * scale),
                             (__bf16)((v2 * c1 - v3 * s1) * scale),
                             (__bf16)((v2 * s1 + v3 * c1) * scale) };
                *(bf16x4*)&dstbase[((size_t)(bb * 16 + h) * T_DIM + tl) * 64 + d0] = o;
            }
        }
    } else {
        for (int k0 = 0; k0 < K; k0 += 32) {
            __syncthreads();
            __builtin_amdgcn_global_load_lds((gptr_t)(const void*)(a0 + k0),
                (lptr_t)(void*)&Af[w * 2 + 0][0][0], 16, 0, 0);
            __builtin_amdgcn_global_load_lds((gptr_t)(const void*)(a1 + k0),
                (lptr_t)(void*)&Af[w * 2 + 1][0][0], 16, 0, 0);
            __builtin_amdgcn_global_load_lds((gptr_t)(const void*)(b0 + k0),
                (lptr_t)(void*)&Bf[w * 2 + 0][0][0], 16, 0, 0);
            __builtin_amdgcn_global_load_lds((gptr_t)(const void*)(b1 + k0),
                (lptr_t)(void*)&Bf[w * 2 + 1][0][0], 16, 0, 0);
            __syncthreads();
            bf16x8 av[4], bv[4];
#pragma unroll
            for (int i = 0; i < 4; ++i) {
                av[i] = *(const bf16x8*)&Af[wm * 4 + i][lane][0];
                bv[i] = *(const bf16x8*)&Bf[wn * 4 + i][lane][0];
            }
#pragma unroll
            for (int i = 0; i < 4; ++i)
#pragma unroll
                for (int j = 0; j < 4; ++j)
                    acc[i][j] = __builtin_amdgcn_mfma_f32_16x16x32_bf16(
                        av[i], bv[j], acc[i][j], 0, 0, 0);
        }

        // ---- epilogue: acc[i][j][r] = C[t = m0+wm*64+i*16+lq*4+r]
        //                               [col = n0+wn*64+j*16+lm]
#pragma unroll
        for (int i = 0; i < 4; ++i) {
            int t4 = m0 + wm * 64 + i * 16 + lq * 4;
            int bb = t4 >> 11, tl = t4 & (T_DIM - 1);
#pragma unroll
            for (int j = 0; j < 4; ++j) {
                int col = n0 + wn * 64 + j * 16 + lm;
                int dfull = col - 2 * C_DIM;
                int h = dfull >> 6, d = dfull & 63;
                float bc = bias[col];
                bf16x4 o = { (__bf16)(acc[i][j][0] + bc),
                             (__bf16)(acc[i][j][1] + bc),
                             (__bf16)(acc[i][j][2] + bc),
                             (__bf16)(acc[i][j][3] + bc) };
                *(bf16x4*)&Vt[((size_t)(bb * 16 + h) * 64 + d) * T_DIM + tl] = o;
            }
        }
    }
}

// ---------------------------------------------------------------------------
// bf16 MFMA GEMM (R5 loop + R6 vectorized C^T epilogue): proj only.
// ---------------------------------------------------------------------------
template <bool OUT_BF16>
__global__ __launch_bounds__(256) void gemm_bt(
    const __bf16* __restrict__ A, const __bf16* __restrict__ Bt,
    const float* __restrict__ bias, void* __restrict__ Cout,
    int M, int N, int K)
{
    __shared__ __align__(16) __bf16 Af[8][64][8];
    __shared__ __align__(16) __bf16 Bf[8][64][8];
    const int tid = threadIdx.x;
    const int lane = tid & 63, w = tid >> 6;
    const int lm = lane & 15, lq = lane >> 4;
    const int wm = w >> 1, wn = w & 1;
    const int m0 = blockIdx.y * 128, n0 = blockIdx.x * 128;

    const __bf16* a0 = A + (size_t)(m0 + w * 32 + lm) * K + lq * 8;
    const __bf16* a1 = a0 + (size_t)16 * K;
    const __bf16* b0 = Bt + (size_t)(n0 + w * 32 + lm) * K + lq * 8;
    const __bf16* b1 = b0 + (size_t)16 * K;

    f32x4 acc[4][4];
#pragma unroll
    for (int i = 0; i < 4; ++i)
#pragma unroll
        for (int j = 0; j < 4; ++j) acc[i][j] = (f32x4){0.f, 0.f, 0.f, 0.f};

    for (int k0 = 0; k0 < K; k0 += 32) {
        __syncthreads();
        __builtin_amdgcn_global_load_lds((gptr_t)(const void*)(a0 + k0),
            (lptr_t)(void*)&Af[w * 2 + 0][0][0], 16, 0, 0);
        __builtin_amdgcn_global_load_lds((gptr_t)(const void*)(a1 + k0),
            (lptr_t)(void*)&Af[w * 2 + 1][0][0], 16, 0, 0);
        __builtin_amdgcn_global_load_lds((gptr_t)(const void*)(b0 + k0),
            (lptr_t)(void*)&Bf[w * 2 + 0][0][0], 16, 0, 0);
        __builtin_amdgcn_global_load_lds((gptr_t)(const void*)(b1 + k0),
            (lptr_t)(void*)&Bf[w * 2 + 1][0][0], 16, 0, 0);
        __syncthreads();

        bf16x8 av[4], bv[4];
#pragma unroll
        for (int i = 0; i < 4; ++i) {
            av[i] = *(const bf16x8*)&Af[wm * 4 + i][lane][0];
            bv[i] = *(const bf16x8*)&Bf[wn * 4 + i][lane][0];
        }
#pragma unroll
        for (int i = 0; i < 4; ++i)
#pragma unroll
            for (int j = 0; j < 4; ++j)
                acc[i][j] = __builtin_amdgcn_mfma_f32_16x16x32_bf16(
                    bv[j], av[i], acc[i][j], 0, 0, 0);
    }

#pragma unroll
    for (int i = 0; i < 4; ++i) {
        size_t row = (size_t)(m0 + wm * 64 + i * 16 + lm);
#pragma unroll
        for (int j = 0; j < 4; ++j) {
            int col = n0 + wn * 64 + j * 16 + lq * 4;
            float4 b4 = *(const float4*)&bias[col];
            float v0 = acc[i][j][0] + b4.x;
            float v1 = acc[i][j][1] + b4.y;
            float v2 = acc[i][j][2] + b4.z;
            float v3 = acc[i][j][3] + b4.w;
            if (OUT_BF16) {
                bf16x4 o = { (__bf16)v0, (__bf16)v1, (__bf16)v2, (__bf16)v3 };
                *(bf16x4*)&((__bf16*)Cout)[row * N + col] = o;
            } else {
                float4 o = make_float4(v0, v1, v2, v3);
                *(float4*)&((float*)Cout)[row * N + col] = o;
            }
        }
    }
}

// ---------------------------------------------------------------------------
// MFMA flash attention (R7): transposed-S dataflow + register-prefetch K/V
// staging. Q now read from compact Qb[bh][t][64] (pre-rope'd, pre-scaled).
// ---------------------------------------------------------------------------
__global__ __launch_bounds__(256) void attn_mfma(
    const __bf16* __restrict__ Qb, const __bf16* __restrict__ Kb,
    const __bf16* __restrict__ Vt, __bf16* __restrict__ yb)
{
    __shared__ __align__(16) __bf16 Kf[8][64][8];   // 8 KB
    __shared__ __align__(16) __bf16 Vf[8][64][8];   // 8 KB
    __shared__ __align__(16) __bf16 Pb[4][16][72];  // 9.2 KB  [w][q][t]

    const int tid = threadIdx.x;
    const int bh = blockIdx.x;                  // 0..63
    const int qt = 31 - blockIdx.y;             // heavy first
    const int b = bh >> 4, h = bh & 15;
    const int lane = tid & 63, w = tid >> 6;
    const int m = lane & 15, qq = lane >> 4;

    const __bf16* qrow = Qb +
        ((size_t)bh * T_DIM + qt * 64 + w * 16 + m) * D_DIM + qq * 8;
    bf16x8 qreg[2];
    qreg[0] = *(const bf16x8*)qrow;
    qreg[1] = *(const bf16x8*)(qrow + 32);

    float m_i = -1e30f, l_i = 0.f;
    f32x4 acc[4];   // O^T: acc[db][r] = O[q=m][d=db*16+qq*4+r]
#pragma unroll
    for (int db = 0; db < 4; ++db) acc[db] = (f32x4){0.f, 0.f, 0.f, 0.f};

    const __bf16* kg0 = Kb + (size_t)bh * T_DIM * D_DIM +
                        (size_t)(w * 16 + m) * D_DIM + qq * 8;
    const __bf16* vg0 = Vt + (size_t)bh * D_DIM * T_DIM +
                        (size_t)(w * 16 + m) * T_DIM + qq * 8;

    bf16x8 kr0 = *(const bf16x8*)(kg0);
    bf16x8 kr1 = *(const bf16x8*)(kg0 + 32);
    bf16x8 vr0 = *(const bf16x8*)(vg0);
    bf16x8 vr1 = *(const bf16x8*)(vg0 + 32);

    for (int kt = 0; kt <= qt; ++kt) {
        __syncthreads();
        *(bf16x8*)&Kf[w * 2 + 0][lane][0] = kr0;
        *(bf16x8*)&Kf[w * 2 + 1][lane][0] = kr1;
        *(bf16x8*)&Vf[w * 2 + 0][lane][0] = vr0;
        *(bf16x8*)&Vf[w * 2 + 1][lane][0] = vr1;
        __syncthreads();

        int ktn = (kt < qt) ? kt + 1 : kt;
        kr0 = *(const bf16x8*)(kg0 + (size_t)ktn * 64 * D_DIM);
        kr1 = *(const bf16x8*)(kg0 + (size_t)ktn * 64 * D_DIM + 32);
        vr0 = *(const bf16x8*)(vg0 + ktn * 64);
        vr1 = *(const bf16x8*)(vg0 + ktn * 64 + 32);

        // ---- S^T = K @ Q^T : sv[nb][r] = S[q=m][t=nb*16+qq*4+r]
        f32x4 sv[4];
#pragma unroll
        for (int nb = 0; nb < 4; ++nb) {
            f32x4 s = (f32x4){0.f, 0.f, 0.f, 0.f};
            s = __builtin_amdgcn_mfma_f32_16x16x32_bf16(
                *(const bf16x8*)&Kf[nb * 2 + 0][lane][0], qreg[0], s, 0, 0, 0);
            s = __builtin_amdgcn_mfma_f32_16x16x32_bf16(
                *(const bf16x8*)&Kf[nb * 2 + 1][lane][0], qreg[1], s, 0, 0, 0);
            sv[nb] = s;
        }

        if (kt == qt) {
            int qlocal = w * 16 + m;
#pragma unroll
            for (int nb = 0; nb < 4; ++nb) {
                int tb = nb * 16 + qq * 4;
#pragma unroll
                for (int r = 0; r < 4; ++r)
                    if (tb + r > qlocal) sv[nb][r] = -1e30f;
            }
        }

        float mt0 = fmaxf(fmaxf(sv[0][0], sv[0][1]), fmaxf(sv[0][2], sv[0][3]));
        float mt1 = fmaxf(fmaxf(sv[1][0], sv[1][1]), fmaxf(sv[1][2], sv[1][3]));
        float mt2 = fmaxf(fmaxf(sv[2][0], sv[2][1]), fmaxf(sv[2][2], sv[2][3]));
        float mt3 = fmaxf(fmaxf(sv[3][0], sv[3][1]), fmaxf(sv[3][2], sv[3][3]));
        float mt = fmaxf(fmaxf(mt0, mt1), fmaxf(mt2, mt3));
        mt = fmaxf(mt, __shfl_xor(mt, 16));
        mt = fmaxf(mt, __shfl_xor(mt, 32));
        float mnew = fmaxf(m_i, mt);
        float alpha = exp2f(m_i - mnew);
        float ll = 0.f;
#pragma unroll
        for (int nb = 0; nb < 4; ++nb) {
            float p0 = exp2f(sv[nb][0] - mnew);
            float p1 = exp2f(sv[nb][1] - mnew);
            float p2 = exp2f(sv[nb][2] - mnew);
            float p3 = exp2f(sv[nb][3] - mnew);
            sv[nb][0] = p0; sv[nb][1] = p1; sv[nb][2] = p2; sv[nb][3] = p3;
            ll += (p0 + p1) + (p2 + p3);
        }
        ll += __shfl_xor(ll, 16);
        ll += __shfl_xor(ll, 32);
        l_i = l_i * alpha + ll;
        m_i = mnew;
#pragma unroll
        for (int db = 0; db < 4; ++db) {
            acc[db][0] *= alpha; acc[db][1] *= alpha;
            acc[db][2] *= alpha; acc[db][3] *= alpha;
        }

#pragma unroll
        for (int nb = 0; nb < 4; ++nb) {
            bf16x4 pv = { (__bf16)sv[nb][0], (__bf16)sv[nb][1],
                          (__bf16)sv[nb][2], (__bf16)sv[nb][3] };
            *(bf16x4*)&Pb[w][m][nb * 16 + qq * 4] = pv;
        }

        bf16x8 pf0 = *(const bf16x8*)&Pb[w][m][0 * 32 + qq * 8];
        bf16x8 pf1 = *(const bf16x8*)&Pb[w][m][1 * 32 + qq * 8];

#pragma unroll
        for (int db = 0; db < 4; ++db) {
            acc[db] = __builtin_amdgcn_mfma_f32_16x16x32_bf16(
                *(const bf16x8*)&Vf[db * 2 + 0][lane][0], pf0, acc[db], 0, 0, 0);
            acc[db] = __builtin_amdgcn_mfma_f32_16x16x32_bf16(
                *(const bf16x8*)&Vf[db * 2 + 1][lane][0], pf1, acc[db], 0, 0, 0);
        }
    }

    float inv = 1.0f / l_i;
    __bf16* yrow = yb + (size_t)(b * T_DIM + qt * 64 + w * 16 + m) * C_DIM +
                   h * D_DIM + qq * 4;
#pragma unroll
    for (int db = 0; db < 4; ++db) {
        bf16x4 o = { (__bf16)(acc[db][0] * inv), (__bf16)(acc[db][1] * inv),
                     (__bf16)(acc[db][2] * inv), (__bf16)(acc[db][3] * inv) };
        *(bf16x4*)(yrow + db * 16) = o;
    }
}

// ---------------------------------------------------------------------------
extern "C" void kernel_launch(void* const* d_in, const int* in_sizes, int n_in,
                              void* d_out, int out_size, void* d_ws, size_t ws_size,
                              hipStream_t stream)
{
    const float* x     = (const float*)d_in[0];
    const float* Wqkv  = (const float*)d_in[1];
    const float* bqkv  = (const float*)d_in[2];
    const float* Wproj = (const float*)d_in[3];
    const float* bproj = (const float*)d_in[4];
    float* out = (float*)d_out;

    char* ws = (char*)d_ws;
    __bf16* xb  = (__bf16*)(ws);                         // [8192][1024] 16 MB
    __bf16* yb  = (__bf16*)(ws + 16777216ull);           // [8192][1024] 16 MB
    __bf16* Qb  = (__bf16*)(ws + 33554432ull);           // [64][2048][64] 16 MB
    __bf16* Kb  = (__bf16*)(ws + 50331648ull);           // [64][2048][64] 16 MB
    __bf16* Vt  = (__bf16*)(ws + 67108864ull);           // [64][64][2048] 16 MB
    __bf16* Wqt = (__bf16*)(ws + 83886080ull);           // [3072][1024] 6 MB
    __bf16* Wpt = (__bf16*)(ws + 90177536ull);           // [1024][1024] 2 MB

    dim3 blk(256);

    // x -> bf16; both weights -> bf16 transposed (one dispatch)
    prep<<<dim3(9216), blk, 0, stream>>>(x, xb, Wqkv, Wqt, Wproj, Wpt);

    // fused QKV GEMM + bias + RoPE + repack -> Qb, Kb, Vt
    gemm_qkv<<<dim3(C3_DIM / 128, (B_DIM * T_DIM) / 128), blk, 0, stream>>>(
        xb, Wqt, bqkv, Qb, Kb, Vt);

    // attention -> yb bf16
    attn_mfma<<<dim3(B_DIM * H_DIM, T_DIM / 64), blk, 0, stream>>>(
        Qb, Kb, Vt, yb);

    // out = yb @ Wproj^T + b_proj (fp32 out)
    gemm_bt<false><<<dim3(C_DIM / 128, (B_DIM * T_DIM) / 128), blk, 0, stream>>>(
        yb, Wpt, bproj, out, B_DIM * T_DIM, C_DIM, C_DIM);
}